// Round 8
// baseline (335.347 us; speedup 1.0000x reference)
//
#include <hip/hip_runtime.h>

// Elman RNN via MFMA, register-chained recurrence, j-split across 4 waves,
// with the x-contribution software-pipelined OFF the critical path.
//   H^T_{t+1} = tanh(W_hh * H^T_t + (b + W_ih * x_{t+1}^T)),  out = sigmoid(fc_w.h_T + fc_b)
//
// mfma_f32_16x16x16f16 layouts (HW-verified rounds 4-6, absmax 3.9e-3):
//   A[m][k]: m = lane&15, k = quad*4 + i
//   B[k][n]: k = quad*4 + i, n = lane&15
//   D[m][n]: n = lane&15, m = quad*4 + reg
// => a wave's D tile (m-tile w), packed to fp16, IS the B-frag kt=w for the
//    next step, same lane. Exchange via LDS, double-buffered, 1 barrier/step.
//
// Round 7: rounds 5/6 showed wall time == 512 x per-wave dependent-latency
// chain (r4 vs r5 work ratio 4.2x == time ratio; barrier ~free). So: move
// cx_{t+1} = bias + W_ih x_{t+1} (2 MFMAs + pack + refill loads) into the
// ds_write->barrier stall window. Critical chain left: ds_read -> 2-deep
// h-MFMA chain -> add -> tanh(5-deep) -> pack -> write -> barrier.

#define RN 2048
#define RT 512
#define RI 32
#define RH 64

typedef _Float16 h4 __attribute__((ext_vector_type(4)));
typedef float    f4 __attribute__((ext_vector_type(4)));

__device__ __forceinline__ void lds_barrier() {
    // LDS-drain-only barrier: global prefetch stays in flight.
    asm volatile("s_waitcnt lgkmcnt(0)\n\ts_barrier" ::: "memory");
}

__device__ __forceinline__ int pk2(float a, float b) {
    return __builtin_bit_cast(int, __builtin_amdgcn_cvt_pkrtz(a, b));
}
__device__ __forceinline__ h4 pack4(float a, float b, float c, float d) {
    union { h4 v; int i[2]; } u;
    u.i[0] = pk2(a, b);
    u.i[1] = pk2(c, d);
    return u.v;
}
__device__ __forceinline__ h4 packf4(f4 v) { return pack4(v[0], v[1], v[2], v[3]); }

__device__ __forceinline__ float tanh_fast(float z) {
    // tanh(z) = 1 - 2/(1 + e^{2z}) = 1 - 2*rcp(exp2(z*2log2e) + 1)
    // 5-deep: mul, v_exp_f32(trans), add, v_rcp_f32(trans), fma. Exact saturation.
    float e = __builtin_amdgcn_exp2f(z * 2.88539008177792681472f);
    float r = __builtin_amdgcn_rcpf(e + 1.0f);
    return __builtin_fmaf(-2.0f, r, 1.0f);
}

__global__ __launch_bounds__(256, 1) void rnn_mfma7(
    const float* __restrict__ x,
    const float* __restrict__ W_ih,
    const float* __restrict__ W_hh,
    const float* __restrict__ b_ih,
    const float* __restrict__ b_hh,
    const float* __restrict__ fc_w,
    const float* __restrict__ fc_b,
    float* __restrict__ out)
{
    const int tid  = threadIdx.x;
    const int w    = tid >> 6;      // wave id = m-tile
    const int lane = tid & 63;
    const int col  = lane & 15;     // sample within group
    const int quad = lane >> 4;     // 0..3
    const int g    = blockIdx.x;

    // h exchange: [buf][kt*64 + lane] -> 8 B B-frag. 2-way bank alias = free.
    __shared__ unsigned long long hb[2][4 * 64];
    __shared__ float ob[4][16];

    // ---- A-frags for my m-tile ----
    h4 Ahh[4];
#pragma unroll
    for (int kt = 0; kt < 4; ++kt) {
        f4 v = *(const f4*)(W_hh + (w * 16 + col) * RH + kt * 16 + quad * 4);
        Ahh[kt] = packf4(v);
    }
    h4 Aih[2];
#pragma unroll
    for (int kt = 0; kt < 2; ++kt) {
        f4 v = *(const f4*)(W_ih + (w * 16 + col) * RI + kt * 16 + quad * 4);
        Aih[kt] = packf4(v);
    }
    f4 biasv;
    {
        f4 bi = *(const f4*)(b_ih + w * 16 + quad * 4);
        f4 bh = *(const f4*)(b_hh + w * 16 + quad * 4);
        biasv = bi + bh;
    }

    // ---- x stream. Slot schedule: iter t packs slot (t+1)&3 (== x[t+1]),
    //      then refills that slot with x[t+5]. Prologue: slot s<-x[s] for
    //      s=1..3, slot0<-x[4]; x[0] feeds cx0 directly. ----
    const float* xb = x + (size_t)(g * 16 + col) * (RT * RI);
    f4 xbuf[4][2];
#pragma unroll
    for (int s = 1; s < 4; ++s) {
        xbuf[s][0] = *(const f4*)(xb + s * RI + quad * 4);
        xbuf[s][1] = *(const f4*)(xb + s * RI + 16 + quad * 4);
    }
    xbuf[0][0] = *(const f4*)(xb + 4 * RI + quad * 4);
    xbuf[0][1] = *(const f4*)(xb + 4 * RI + 16 + quad * 4);

    f4 cx; // bias + W_ih x_t, precomputed one step ahead
    {
        f4 x0a = *(const f4*)(xb + quad * 4);
        f4 x0b = *(const f4*)(xb + 16 + quad * 4);
        cx = __builtin_amdgcn_mfma_f32_16x16x16f16(Aih[0], packf4(x0a), biasv, 0, 0, 0);
        cx = __builtin_amdgcn_mfma_f32_16x16x16f16(Aih[1], packf4(x0b), cx, 0, 0, 0);
    }

    // h0 = ones, already in B-frag layout
    h4 Bh[4];
#pragma unroll
    for (int kt = 0; kt < 4; ++kt) Bh[kt] = pack4(1.f, 1.f, 1.f, 1.f);
    f4 hv; // f32 h of final step (my m-tile rows), for epilogue

    for (int t4 = 0; t4 < RT; t4 += 4) {
#pragma unroll
        for (int s = 0; s < 4; ++s) {
            const int t = t4 + s;

            // ---- critical path: h-part, two 2-deep chains seeded by cx ----
            f4 c0 = __builtin_amdgcn_mfma_f32_16x16x16f16(Ahh[0], Bh[0], cx, 0, 0, 0);
            f4 c1 = __builtin_amdgcn_mfma_f32_16x16x16f16(Ahh[1], Bh[1], f4{0.f, 0.f, 0.f, 0.f}, 0, 0, 0);
            c0 = __builtin_amdgcn_mfma_f32_16x16x16f16(Ahh[2], Bh[2], c0, 0, 0, 0);
            c1 = __builtin_amdgcn_mfma_f32_16x16x16f16(Ahh[3], Bh[3], c1, 0, 0, 0);
            f4 acc = c0 + c1;

            hv[0] = tanh_fast(acc[0]);
            hv[1] = tanh_fast(acc[1]);
            hv[2] = tanh_fast(acc[2]);
            hv[3] = tanh_fast(acc[3]);

            // publish my D tile as next step's B-frag kt = w
            const int p = t & 1;
            hb[p][w * 64 + lane] = __builtin_bit_cast(unsigned long long, packf4(hv));

            // ---- stall-window work: cx for step t+1, x ring refill ----
            const int sn = (s + 1) & 3;
            h4 bx0 = packf4(xbuf[sn][0]);
            h4 bx1 = packf4(xbuf[sn][1]);
            int tl = t + 5; if (tl > RT - 1) tl = RT - 1;
            xbuf[sn][0] = *(const f4*)(xb + tl * RI + quad * 4);
            xbuf[sn][1] = *(const f4*)(xb + tl * RI + 16 + quad * 4);
            f4 cxn = __builtin_amdgcn_mfma_f32_16x16x16f16(Aih[0], bx0, biasv, 0, 0, 0);
            cxn = __builtin_amdgcn_mfma_f32_16x16x16f16(Aih[1], bx1, cxn, 0, 0, 0);

            lds_barrier();
            Bh[0] = __builtin_bit_cast(h4, hb[p][0 * 64 + lane]);
            Bh[1] = __builtin_bit_cast(h4, hb[p][1 * 64 + lane]);
            Bh[2] = __builtin_bit_cast(h4, hb[p][2 * 64 + lane]);
            Bh[3] = __builtin_bit_cast(h4, hb[p][3 * 64 + lane]);
            cx = cxn;
        }
    }

    // ---- epilogue: out[n] = sigmoid(sum_j fc_w[j] h[n][j] + fc_b) ----
    {
        f4 wv = *(const f4*)(fc_w + w * 16 + quad * 4);
        float s = wv[0] * hv[0] + wv[1] * hv[1] + wv[2] * hv[2] + wv[3] * hv[3];
        s += __shfl_xor(s, 16, 64);
        s += __shfl_xor(s, 32, 64); // all lanes: partial over my 16 hidden units
        if (quad == 0) ob[w][col] = s;
        lds_barrier();
        if (w == 0 && lane < 16) {
            float logit = ob[0][lane] + ob[1][lane] + ob[2][lane] + ob[3][lane] + fc_b[0];
            out[g * 16 + lane] = __fdividef(1.0f, 1.0f + __expf(-logit));
        }
    }
}

extern "C" void kernel_launch(void* const* d_in, const int* in_sizes, int n_in,
                              void* d_out, int out_size, void* d_ws, size_t ws_size,
                              hipStream_t stream) {
    rnn_mfma7<<<RN / 16, 256, 0, stream>>>(
        (const float*)d_in[0], (const float*)d_in[1], (const float*)d_in[2],
        (const float*)d_in[3], (const float*)d_in[4], (const float*)d_in[5],
        (const float*)d_in[6], (float*)d_out);
}